// Round 6
// baseline (405.633 us; speedup 1.0000x reference)
//
#include <hip/hip_runtime.h>

#define N_NODES 51200
#define N_EDGES 819200
#define HDIM 128
#define NGRAPH 128
#define SEG 400
#define NOUT 10
#define SLOT 64         // fixed col2 slot per node (deg ~ Poisson(16); P(>64) ~ 1e-13)

// counting-sort CSR build (replaces atomic scatter; atomics were the 56us floor)
#define HISTW (N_NODES / 4)   // 12800 words, 4 byte-bins per word (50 KB LDS)
#define NBLK 200              // edge partitions
#define EPB (N_EDGES / NBLK)  // 4096 edges per partition
#define SEGS 8
#define BPSEG (NBLK / SEGS)   // 25 partitions per scan segment

#define LDSW 264              // GEMM A-tile ushort stride (16B-aligned rows)
#define QS ((size_t)N_NODES * 32)   // ushorts per contiguous column-quarter region

typedef unsigned short ushort_t;
typedef unsigned int uint_t;
typedef __attribute__((ext_vector_type(8))) short bf16x8;
typedef __attribute__((ext_vector_type(16))) float f32x16;
typedef __attribute__((ext_vector_type(4))) uint_t uint4e;

static __device__ __forceinline__ unsigned short f2bf(float f) {
    unsigned int u = __float_as_uint(f);
    unsigned int r = (u + 0x7fffu + ((u >> 16) & 1u)) >> 16;  // RNE
    return (unsigned short)r;
}
static __device__ __forceinline__ float bf2f(unsigned short h) {
    return __uint_as_float(((unsigned int)h) << 16);
}

// ------- prep+count: CSR histogram (first, overlaps), cast x0 -> xq, Wfrags, pooled --
// xq layout: quarter-contiguous xq[q][node][32] so each quarter table is a DENSE
// 3.27 MB region (fits one XCD's 4 MB L2). R3's strided quarters thrashed lines.

__global__ void k_prep(const float* __restrict__ x, ushort_t* __restrict__ xq,
                       const float* __restrict__ W1rel, const float* __restrict__ W1root,
                       const float* __restrict__ W2rel, const float* __restrict__ W2root,
                       ushort_t* __restrict__ Wfrag1, ushort_t* __restrict__ Wfrag2,
                       float* __restrict__ pooled, const int* __restrict__ dst,
                       uint_t* __restrict__ bh) {
    __shared__ uint_t hist[HISTW];
    int b = blockIdx.x;
    int tid = threadIdx.x;
    if (b < NBLK) {
        for (int i = tid; i < HISTW; i += 256) hist[i] = 0u;
        __syncthreads();
        const int4* d4 = (const int4*)dst + b * (EPB / 4);
#pragma unroll
        for (int p = 0; p < 4; ++p) {
            int4 d = d4[p * 256 + tid];
            atomicAdd(&hist[((uint_t)d.x) >> 2], 1u << ((d.x & 3) * 8));
            atomicAdd(&hist[((uint_t)d.y) >> 2], 1u << ((d.y & 3) * 8));
            atomicAdd(&hist[((uint_t)d.z) >> 2], 1u << ((d.z & 3) * 8));
            atomicAdd(&hist[((uint_t)d.w) >> 2], 1u << ((d.w & 3) * 8));
        }
        __syncthreads();
        for (int i = tid; i < HISTW; i += 256) bh[(size_t)b * HISTW + i] = hist[i];
    } else if (b < 6600) {
        int idx = (b - NBLK) * 256 + tid;
        int row = idx >> 5;
        int c4 = (idx & 31) * 4;
        float4 v = *(const float4*)(x + (size_t)row * HDIM + c4);
        ushort4 h;
        h.x = f2bf(v.x); h.y = f2bf(v.y); h.z = f2bf(v.z); h.w = f2bf(v.w);
        *(ushort4*)(xq + (size_t)(c4 >> 5) * QS + (size_t)row * 32 + (c4 & 31)) = h;
    } else if (b < 6856) {
        int w2 = (b >= 6728);
        int t0 = (b - (w2 ? 6728 : 6600)) * 256 + tid;  // 0..32767
        const float* Wrel  = w2 ? W2rel : W1rel;
        const float* Wroot = w2 ? W2root : W1root;
        ushort_t* dstF     = w2 ? Wfrag2 : Wfrag1;
        int j = t0 & 7;
        int l = (t0 >> 3) & 63;
        int s = (t0 >> 9) & 15;
        int t = t0 >> 13;
        int k = 16 * s + (l >> 5) * 8 + j;
        int n = 32 * t + (l & 31);
        float v = (k < HDIM) ? Wrel[(size_t)k * HDIM + n]
                             : Wroot[(size_t)(k - HDIM) * HDIM + n];
        dstF[t0] = f2bf(v);
    } else {
        int i = (b - 6856) * 256 + tid;  // 0..16383
        pooled[i] = 0.f;
    }
}

// ---------------- CSR pass 2: in-place SWAR exclusive scan over partitions ----------

__global__ __launch_bounds__(256) void k_prefix(uint_t* __restrict__ bh,
                                                int* __restrict__ cnt) {
    __shared__ uint_t segsum[SEGS][32];
    int ci = threadIdx.x & 31;
    int seg = threadIdx.x >> 5;
    int c = blockIdx.x * 32 + ci;
    uint_t v[BPSEG];
    uint_t sum = 0;
#pragma unroll
    for (int k = 0; k < BPSEG; ++k) {
        v[k] = bh[(size_t)(seg * BPSEG + k) * HISTW + c];
        sum += v[k];
    }
    segsum[seg][ci] = sum;
    __syncthreads();
    uint_t run = 0;
    for (int s = 0; s < seg; ++s) run += segsum[s][ci];
#pragma unroll
    for (int k = 0; k < BPSEG; ++k) {
        bh[(size_t)(seg * BPSEG + k) * HISTW + c] = run;
        run += v[k];
    }
    if (seg == SEGS - 1) {
        int4 o;
        o.x = (int)(run & 0xffu);
        o.y = (int)((run >> 8) & 0xffu);
        o.z = (int)((run >> 16) & 0xffu);
        o.w = (int)((run >> 24) & 0xffu);
        *(int4*)(cnt + 4 * c) = o;
    }
}

// ---------------- CSR pass 3: place edges; LDS atomic returns final slot ------------

__global__ __launch_bounds__(256) void k_place(const int* __restrict__ src,
                                               const int* __restrict__ dst,
                                               const uint_t* __restrict__ bh,
                                               ushort_t* __restrict__ col2) {
    __shared__ uint_t hist[HISTW];
    int b = blockIdx.x, tid = threadIdx.x;
    for (int i = tid; i < HISTW; i += 256) hist[i] = bh[(size_t)b * HISTW + i];
    __syncthreads();
    const int4* d4 = (const int4*)dst + b * (EPB / 4);
    const int4* s4 = (const int4*)src + b * (EPB / 4);
#pragma unroll
    for (int p = 0; p < 4; ++p) {
        int4 d = d4[p * 256 + tid];
        int4 s = s4[p * 256 + tid];
#define PLACE1(dd, ss)                                                        \
        do {                                                                  \
            uint_t w = (uint_t)(dd);                                          \
            int sh = (int)(w & 3u) * 8;                                       \
            uint_t old = atomicAdd(&hist[w >> 2], 1u << sh);                  \
            col2[(size_t)w * SLOT + ((old >> sh) & 0xffu)] = (ushort_t)(ss);  \
        } while (0)
        PLACE1(d.x, s.x);
        PLACE1(d.y, s.y);
        PLACE1(d.z, s.z);
        PLACE1(d.w, s.w);
#undef PLACE1
    }
}

// -------- aggregation: R1-lean execution on the quarter-contiguous L2-bound layout ---
// R5 post-mortem: pair-binding locality CONFIRMED (FETCH 26.4 MB == compulsory) but
// the 2-node/shfl-broadcast/masked-ACC structure was execution-bound (81.6us, VALU 51%).
// This version: wave = 1 node x 1 quarter, il=lane&3 (16B), qe=lane>>2 (16 edges in
// flight), direct nontemporal col loads (no shfl in the load chain), UNCONDITIONAL
// adds in the main loop, one masked tail, 4-round shfl_xor reduce, nt 64B store.

__global__ __launch_bounds__(256) void k_aggq(const ushort_t* __restrict__ xq,
                                              ushort_t* __restrict__ aggbuf,
                                              const int* __restrict__ cnt,
                                              const ushort_t* __restrict__ col) {
    int wv = threadIdx.x >> 6;
    int lane = threadIdx.x & 63;
    int il = lane & 3;           // 16 B chunk within the 64 B quarter
    int qe = lane >> 2;          // edge slot 0..15
    int x = blockIdx.x & 7;      // XCD (round-robin heuristic)
    int q = x >> 1;              // quarter bound to XCD pair {2q, 2q+1}
    int sub = ((blockIdx.x >> 3) << 1) + (x & 1);   // 0..12799
    int node = sub * 4 + wv;
    int beg = node * SLOT;
    int end = beg + cnt[node];

    const ushort_t* xqq = xq + (size_t)q * QS + (size_t)il * 8;

    float a[8];
#pragma unroll
    for (int k = 0; k < 8; ++k) a[k] = 0.f;

    int e = beg;
    for (; e + 16 <= end; e += 16) {
        int c = (int)__builtin_nontemporal_load(col + e + qe);
        uint4 v = *(const uint4*)(xqq + (size_t)c * 32);
        a[0] += __uint_as_float(v.x << 16);
        a[1] += __uint_as_float(v.x & 0xffff0000u);
        a[2] += __uint_as_float(v.y << 16);
        a[3] += __uint_as_float(v.y & 0xffff0000u);
        a[4] += __uint_as_float(v.z << 16);
        a[5] += __uint_as_float(v.z & 0xffff0000u);
        a[6] += __uint_as_float(v.w << 16);
        a[7] += __uint_as_float(v.w & 0xffff0000u);
    }
    if (e < end) {
        int idx = e + qe;
        bool ok = idx < end;
        int c = (int)__builtin_nontemporal_load(col + (ok ? idx : e));
        uint4 v = *(const uint4*)(xqq + (size_t)c * 32);
        a[0] += ok ? __uint_as_float(v.x << 16) : 0.f;
        a[1] += ok ? __uint_as_float(v.x & 0xffff0000u) : 0.f;
        a[2] += ok ? __uint_as_float(v.y << 16) : 0.f;
        a[3] += ok ? __uint_as_float(v.y & 0xffff0000u) : 0.f;
        a[4] += ok ? __uint_as_float(v.z << 16) : 0.f;
        a[5] += ok ? __uint_as_float(v.z & 0xffff0000u) : 0.f;
        a[6] += ok ? __uint_as_float(v.w << 16) : 0.f;
        a[7] += ok ? __uint_as_float(v.w & 0xffff0000u) : 0.f;
    }

    // reduce over the 16 edge slots (lane bits 2..5); all lanes execute
#pragma unroll
    for (int k = 0; k < 8; ++k) {
        a[k] += __shfl_xor(a[k], 4);
        a[k] += __shfl_xor(a[k], 8);
        a[k] += __shfl_xor(a[k], 16);
        a[k] += __shfl_xor(a[k], 32);
    }

    if (qe == 0) {
        uint4e o;
        o.x = (uint_t)f2bf(a[0]) | ((uint_t)f2bf(a[1]) << 16);
        o.y = (uint_t)f2bf(a[2]) | ((uint_t)f2bf(a[3]) << 16);
        o.z = (uint_t)f2bf(a[4]) | ((uint_t)f2bf(a[5]) << 16);
        o.w = (uint_t)f2bf(a[6]) | ((uint_t)f2bf(a[7]) << 16);
        __builtin_nontemporal_store(o, (uint4e*)(aggbuf + (size_t)node * HDIM + q * 32 + il * 8));
    }
}

// -------- single-pass MFMA GEMM: 256-thr block = 32 rows x full N=128 (A read once) --
// A = [agg(128) | x(128)]: left from aggbuf (row-major), right from xq quarters.

template<int POOL>
__global__ __launch_bounds__(256) void k_gemm256(const ushort_t* __restrict__ aggbuf,
                                                 const ushort_t* __restrict__ xq,
                                                 const ushort_t* __restrict__ Wfrag,
                                                 const float* __restrict__ bias,
                                                 ushort_t* __restrict__ y,
                                                 float* __restrict__ pooled) {
    __shared__ ushort_t At[32][LDSW];
    int tid = threadIdx.x;
    int w = tid >> 6;
    int lane = tid & 63;
    int row0 = blockIdx.x * 32;

#pragma unroll
    for (int it = 0; it < 4; ++it) {
        int idx = it * 256 + tid;     // 0..1023
        int r = idx >> 5;
        int c16 = idx & 31;
        uint4 v;
        if (c16 < 16) {
            v = *(const uint4*)(aggbuf + (size_t)(row0 + r) * HDIM + c16 * 8);
        } else {
            int cq = c16 - 16;        // 0..15
            v = *(const uint4*)(xq + (size_t)(cq >> 2) * QS + (size_t)(row0 + r) * 32 + (cq & 3) * 8);
        }
        *(uint4*)&At[r][c16 * 8] = v;
    }
    __syncthreads();

    int m = lane & 31;
    int half = lane >> 5;
    f32x16 acc = (f32x16)(0.f);
    float bb = bias[w * 32 + m];
    const ushort_t* arow = &At[m][half * 8];
    const ushort_t* wf = Wfrag + (size_t)lane * 8;

#pragma unroll
    for (int s = 0; s < 16; ++s) {
        bf16x8 afrag = *(const bf16x8*)(arow + s * 16);
        bf16x8 bfrag = *(const bf16x8*)(wf + (size_t)(w * 16 + s) * 512);
        acc = __builtin_amdgcn_mfma_f32_32x32x16_bf16(afrag, bfrag, acc, 0, 0, 0);
    }

    if (POOL == 0) {
        __syncthreads();   // all waves done reading At; reuse it for the y transpose
#pragma unroll
        for (int r = 0; r < 16; ++r) {
            int rowL = (r & 3) + 8 * (r >> 2) + 4 * half;
            At[rowL][w * 32 + m] = f2bf(fmaxf(acc[r] + bb, 0.f));
        }
        __syncthreads();
#pragma unroll
        for (int it = 0; it < 2; ++it) {
            int c = it * 256 + tid;
            int row = c >> 4;
            int sg = c & 15;
            *(int4*)(y + (size_t)(row0 + row) * HDIM + sg * 8) = *(const int4*)&At[row][sg * 8];
        }
    } else {
        int g0 = row0 / SEG;
        int bnd = (g0 + 1) * SEG;
        int straddle = (row0 + 31 >= bnd);
        float s0 = 0.f, s1 = 0.f;
#pragma unroll
        for (int r = 0; r < 16; ++r) {
            int row = row0 + (r & 3) + 8 * (r >> 2) + 4 * half;
            float v = fmaxf(acc[r] + bb, 0.f);
            if (row < bnd) s0 += v; else s1 += v;
        }
        s0 += __shfl_xor(s0, 32);
        s1 += __shfl_xor(s1, 32);
        if (half == 0) {
            int coln = w * 32 + m;
            atomicAdd(&pooled[g0 * HDIM + coln], s0);
            if (straddle) atomicAdd(&pooled[(g0 + 1) * HDIM + coln], s1);
        }
    }
}

// ---------------- mixup: bf16 y -> xq quarters ----------------

__global__ void k_mixup_toA(const ushort_t* __restrict__ y, const int* __restrict__ perm,
                            const float* __restrict__ lam, ushort_t* __restrict__ xq) {
    int idx = blockIdx.x * 256 + threadIdx.x;
    int row = idx >> 5;
    int c4 = (idx & 31) * 4;
    float l = lam[0];
    float om = 1.f - l;
    int p = perm[row];
    ushort4 a = *(const ushort4*)(y + (size_t)row * HDIM + c4);
    ushort4 b = *(const ushort4*)(y + (size_t)p * HDIM + c4);
    ushort4 o;
    o.x = f2bf(l * bf2f(a.x) + om * bf2f(b.x));
    o.y = f2bf(l * bf2f(a.y) + om * bf2f(b.y));
    o.z = f2bf(l * bf2f(a.z) + om * bf2f(b.z));
    o.w = f2bf(l * bf2f(a.w) + om * bf2f(b.w));
    *(ushort4*)(xq + (size_t)(c4 >> 5) * QS + (size_t)row * 32 + (c4 & 31)) = o;
}

// ---------------- final: linear + log_softmax from pooled ----------------

__global__ __launch_bounds__(64) void k_final(const float* __restrict__ pooled,
                                              const float* __restrict__ Wlin,
                                              const float* __restrict__ blin,
                                              float* __restrict__ out) {
    int g = blockIdx.x;
    int lane = threadIdx.x;
    float2 v = *(const float2*)(pooled + (size_t)g * HDIM + lane * 2);
    float p[NOUT];
#pragma unroll
    for (int o = 0; o < NOUT; ++o)
        p[o] = v.x * Wlin[(size_t)(2 * lane) * NOUT + o] +
               v.y * Wlin[(size_t)(2 * lane + 1) * NOUT + o];
#pragma unroll
    for (int mask = 1; mask < 64; mask <<= 1)
#pragma unroll
        for (int o = 0; o < NOUT; ++o) p[o] += __shfl_xor(p[o], mask);
    if (lane == 0) {
        float lg[NOUT];
        float mx = -1e30f;
#pragma unroll
        for (int o = 0; o < NOUT; ++o) { lg[o] = p[o] + blin[o]; mx = fmaxf(mx, lg[o]); }
        float se = 0.f;
#pragma unroll
        for (int o = 0; o < NOUT; ++o) se += expf(lg[o] - mx);
        float lse = mx + logf(se);
#pragma unroll
        for (int o = 0; o < NOUT; ++o) out[g * NOUT + o] = lg[o] - lse;
    }
}

// ---------------- host ----------------

extern "C" void kernel_launch(void* const* d_in, const int* in_sizes, int n_in,
                              void* d_out, int out_size, void* d_ws, size_t ws_size,
                              hipStream_t stream) {
    const float* x0     = (const float*)d_in[0];
    const int*   edge   = (const int*)d_in[1];
    const int*   src    = edge;
    const int*   dst    = edge + N_EDGES;
    const float* lam    = (const float*)d_in[2];
    const int*   perm1  = (const int*)d_in[5];
    const int*   perm2  = (const int*)d_in[6];
    const float* W1_rel = (const float*)d_in[8];
    const float* b1_rel = (const float*)d_in[9];
    const float* W1_root= (const float*)d_in[10];
    const float* W2_rel = (const float*)d_in[11];
    const float* b2_rel = (const float*)d_in[12];
    const float* W2_root= (const float*)d_in[13];
    const float* W_lin  = (const float*)d_in[14];
    const float* b_lin  = (const float*)d_in[15];
    float* out = (float*)d_out;

    char* w = (char*)d_ws;
    size_t off = 0;
    auto alloc = [&](size_t bytes) -> void* {
        void* p = w + off;
        off = (off + bytes + 255) & ~(size_t)255;
        return p;
    };
    int* cnt        = (int*)alloc((size_t)N_NODES * 4);
    ushort_t* col2  = (ushort_t*)alloc((size_t)N_NODES * SLOT * 2);
    ushort_t* xq    = (ushort_t*)alloc((size_t)N_NODES * HDIM * 2);
    ushort_t* aggbuf= (ushort_t*)alloc((size_t)N_NODES * HDIM * 2);
    ushort_t* ybuf  = (ushort_t*)alloc((size_t)N_NODES * HDIM * 2);
    ushort_t* Wfrag1= (ushort_t*)alloc(32768 * 2);
    ushort_t* Wfrag2= (ushort_t*)alloc(32768 * 2);
    float* pooled   = (float*)alloc((size_t)NGRAPH * HDIM * 4);

    // block-histogram matrix aliases ybuf (10.24 MB <= 13.1 MB): ybuf is dead
    // until the layer-1 GEMM writes it, strictly after k_place completes.
    uint_t* bh = (uint_t*)ybuf;

    // prep (+ CSR count blocks first, overlapping the BW-bound cast blocks)
    k_prep<<<6920, 256, 0, stream>>>(x0, xq, W1_rel, W1_root, W2_rel, W2_root,
                                     Wfrag1, Wfrag2, pooled, dst, bh);
    k_prefix<<<HISTW / 32, 256, 0, stream>>>(bh, cnt);
    k_place<<<NBLK, 256, 0, stream>>>(src, dst, bh, col2);

    const int aggGrid  = N_NODES;       // (12800 node-blocks) x 4 quarters, XCD-bound
    const int gemmGrid = N_NODES / 32;  // 1600
    const int elGrid   = (N_NODES * HDIM / 4) / 256;  // 6400

    // layer 1
    k_aggq<<<aggGrid, 256, 0, stream>>>(xq, aggbuf, cnt, col2);
    k_gemm256<0><<<gemmGrid, 256, 0, stream>>>(aggbuf, xq, Wfrag1, b1_rel, ybuf, pooled);
    k_mixup_toA<<<elGrid, 256, 0, stream>>>(ybuf, perm1, lam, xq);
    // layer 2
    k_aggq<<<aggGrid, 256, 0, stream>>>(xq, aggbuf, cnt, col2);
    k_gemm256<0><<<gemmGrid, 256, 0, stream>>>(aggbuf, xq, Wfrag2, b2_rel, ybuf, pooled);
    k_mixup_toA<<<elGrid, 256, 0, stream>>>(ybuf, perm2, lam, xq);
    // layer 3 (mixup3 is a pooling no-op -> fused pool)
    k_aggq<<<aggGrid, 256, 0, stream>>>(xq, aggbuf, cnt, col2);
    k_gemm256<1><<<gemmGrid, 256, 0, stream>>>(aggbuf, xq, Wfrag2, b2_rel, ybuf, pooled);

    // classifier + log_softmax
    k_final<<<NGRAPH, 64, 0, stream>>>(pooled, W_lin, b_lin, out);
}

// Round 7
// 266.716 us; speedup vs baseline: 1.5208x; 1.5208x over previous
//
#include <hip/hip_runtime.h>

#define N_NODES 51200
#define N_EDGES 819200
#define HDIM 128
#define NGRAPH 128
#define SEG 400
#define NOUT 10
#define SLOT 64         // fixed col2 slot per node (deg ~ Poisson(16); P(>64) ~ 1e-13)

// counting-sort CSR build (replaces atomic scatter; atomics were the 56us floor)
#define HISTW (N_NODES / 4)   // 12800 words, 4 byte-bins per word (50 KB LDS)
#define NBLK 200              // edge partitions
#define EPB (N_EDGES / NBLK)  // 4096 edges per partition
#define SEGS 8
#define BPSEG (NBLK / SEGS)   // 25 partitions per scan segment

#define LDSW 264              // GEMM A-tile ushort stride (16B-aligned rows)

typedef unsigned short ushort_t;
typedef unsigned int uint_t;
typedef __attribute__((ext_vector_type(8))) short bf16x8;
typedef __attribute__((ext_vector_type(16))) float f32x16;
typedef __attribute__((ext_vector_type(4))) uint_t uint4e;

static __device__ __forceinline__ unsigned short f2bf(float f) {
    unsigned int u = __float_as_uint(f);
    unsigned int r = (u + 0x7fffu + ((u >> 16) & 1u)) >> 16;  // RNE
    return (unsigned short)r;
}
static __device__ __forceinline__ float bf2f(unsigned short h) {
    return __uint_as_float(((unsigned int)h) << 16);
}

// ------- prep+count: CSR histogram (first, overlaps), cast x0 -> xrow, Wfrags, pooled

__global__ void k_prep(const float* __restrict__ x, ushort_t* __restrict__ xrow,
                       const float* __restrict__ W1rel, const float* __restrict__ W1root,
                       const float* __restrict__ W2rel, const float* __restrict__ W2root,
                       ushort_t* __restrict__ Wfrag1, ushort_t* __restrict__ Wfrag2,
                       float* __restrict__ pooled, const int* __restrict__ dst,
                       uint_t* __restrict__ bh) {
    __shared__ uint_t hist[HISTW];
    int b = blockIdx.x;
    int tid = threadIdx.x;
    if (b < NBLK) {
        for (int i = tid; i < HISTW; i += 256) hist[i] = 0u;
        __syncthreads();
        const int4* d4 = (const int4*)dst + b * (EPB / 4);
#pragma unroll
        for (int p = 0; p < 4; ++p) {
            int4 d = d4[p * 256 + tid];
            atomicAdd(&hist[((uint_t)d.x) >> 2], 1u << ((d.x & 3) * 8));
            atomicAdd(&hist[((uint_t)d.y) >> 2], 1u << ((d.y & 3) * 8));
            atomicAdd(&hist[((uint_t)d.z) >> 2], 1u << ((d.z & 3) * 8));
            atomicAdd(&hist[((uint_t)d.w) >> 2], 1u << ((d.w & 3) * 8));
        }
        __syncthreads();
        for (int i = tid; i < HISTW; i += 256) bh[(size_t)b * HISTW + i] = hist[i];
    } else if (b < 6600) {
        int idx = (b - NBLK) * 256 + tid;
        int row = idx >> 5;
        int c4 = (idx & 31) * 4;
        float4 v = *(const float4*)(x + (size_t)row * HDIM + c4);
        ushort4 h;
        h.x = f2bf(v.x); h.y = f2bf(v.y); h.z = f2bf(v.z); h.w = f2bf(v.w);
        *(ushort4*)(xrow + (size_t)row * HDIM + c4) = h;
    } else if (b < 6856) {
        int w2 = (b >= 6728);
        int t0 = (b - (w2 ? 6728 : 6600)) * 256 + tid;  // 0..32767
        const float* Wrel  = w2 ? W2rel : W1rel;
        const float* Wroot = w2 ? W2root : W1root;
        ushort_t* dstF     = w2 ? Wfrag2 : Wfrag1;
        int j = t0 & 7;
        int l = (t0 >> 3) & 63;
        int s = (t0 >> 9) & 15;
        int t = t0 >> 13;
        int k = 16 * s + (l >> 5) * 8 + j;
        int n = 32 * t + (l & 31);
        float v = (k < HDIM) ? Wrel[(size_t)k * HDIM + n]
                             : Wroot[(size_t)(k - HDIM) * HDIM + n];
        dstF[t0] = f2bf(v);
    } else {
        int i = (b - 6856) * 256 + tid;  // 0..16383
        pooled[i] = 0.f;
    }
}

// ---------------- CSR pass 2: in-place SWAR exclusive scan over partitions ----------

__global__ __launch_bounds__(256) void k_prefix(uint_t* __restrict__ bh,
                                                int* __restrict__ cnt) {
    __shared__ uint_t segsum[SEGS][32];
    int ci = threadIdx.x & 31;
    int seg = threadIdx.x >> 5;
    int c = blockIdx.x * 32 + ci;
    uint_t v[BPSEG];
    uint_t sum = 0;
#pragma unroll
    for (int k = 0; k < BPSEG; ++k) {
        v[k] = bh[(size_t)(seg * BPSEG + k) * HISTW + c];
        sum += v[k];
    }
    segsum[seg][ci] = sum;
    __syncthreads();
    uint_t run = 0;
    for (int s = 0; s < seg; ++s) run += segsum[s][ci];
#pragma unroll
    for (int k = 0; k < BPSEG; ++k) {
        bh[(size_t)(seg * BPSEG + k) * HISTW + c] = run;
        run += v[k];
    }
    if (seg == SEGS - 1) {
        int4 o;
        o.x = (int)(run & 0xffu);
        o.y = (int)((run >> 8) & 0xffu);
        o.z = (int)((run >> 16) & 0xffu);
        o.w = (int)((run >> 24) & 0xffu);
        *(int4*)(cnt + 4 * c) = o;
    }
}

// ---------------- CSR pass 3: place edges; LDS atomic returns final slot ------------

__global__ __launch_bounds__(256) void k_place(const int* __restrict__ src,
                                               const int* __restrict__ dst,
                                               const uint_t* __restrict__ bh,
                                               ushort_t* __restrict__ col2) {
    __shared__ uint_t hist[HISTW];
    int b = blockIdx.x, tid = threadIdx.x;
    for (int i = tid; i < HISTW; i += 256) hist[i] = bh[(size_t)b * HISTW + i];
    __syncthreads();
    const int4* d4 = (const int4*)dst + b * (EPB / 4);
    const int4* s4 = (const int4*)src + b * (EPB / 4);
#pragma unroll
    for (int p = 0; p < 4; ++p) {
        int4 d = d4[p * 256 + tid];
        int4 s = s4[p * 256 + tid];
#define PLACE1(dd, ss)                                                        \
        do {                                                                  \
            uint_t w = (uint_t)(dd);                                          \
            int sh = (int)(w & 3u) * 8;                                       \
            uint_t old = atomicAdd(&hist[w >> 2], 1u << sh);                  \
            col2[(size_t)w * SLOT + ((old >> sh) & 0xffu)] = (ushort_t)(ss);  \
        } while (0)
        PLACE1(d.x, s.x);
        PLACE1(d.y, s.y);
        PLACE1(d.z, s.z);
        PLACE1(d.w, s.w);
#undef PLACE1
    }
}

// ---------------- aggregation: R1 quad-edge gathers + masked 16-edge tail -----------
// Post-R5/R6 verdict: L2-resident quarter tiling loses (82us) to the HBM random-line
// plateau (~40us at 2.1 TB/s) because per-wave fixed cost quadruples. This is the
// lean one-wave-per-node structure, with: separate gather table (xrow) vs output
// (aggbuf, nt stores) so write-allocates don't evict hot x lines; nt col2 loads;
// single fully-masked 16-edge tail (4 parallel masked gathers, was serial 4-batches).

__global__ __launch_bounds__(256) void k_aggregate(const ushort_t* __restrict__ xrow,
                                                   ushort_t* __restrict__ aggbuf,
                                                   const int* __restrict__ cnt,
                                                   const ushort_t* __restrict__ col) {
    int wave = threadIdx.x >> 6;
    int lane = threadIdx.x & 63;
    int il = lane & 15;          // col group: cols 8*il..8*il+7 (16 B)
    int qe = lane >> 4;          // edge within quad: 0..3
    int node = blockIdx.x * 4 + wave;
    int beg = node * SLOT;
    int end = beg + cnt[node];

    const ushort_t* xsrc = xrow + (size_t)il * 8;

    float a[4][8];
#pragma unroll
    for (int j = 0; j < 4; ++j)
#pragma unroll
        for (int k = 0; k < 8; ++k) a[j][k] = 0.f;

    int e = beg;
    for (; e + 16 <= end; e += 16) {
        int c[4];
#pragma unroll
        for (int j = 0; j < 4; ++j)
            c[j] = (int)__builtin_nontemporal_load(col + e + 4 * j + qe);
#pragma unroll
        for (int j = 0; j < 4; ++j) {
            uint4 v = *(const uint4*)(xsrc + (size_t)c[j] * HDIM);
            a[j][0] += __uint_as_float(v.x << 16);
            a[j][1] += __uint_as_float(v.x & 0xffff0000u);
            a[j][2] += __uint_as_float(v.y << 16);
            a[j][3] += __uint_as_float(v.y & 0xffff0000u);
            a[j][4] += __uint_as_float(v.z << 16);
            a[j][5] += __uint_as_float(v.z & 0xffff0000u);
            a[j][6] += __uint_as_float(v.w << 16);
            a[j][7] += __uint_as_float(v.w & 0xffff0000u);
        }
    }
    if (e < end) {
        // single fully-masked batch of up to 15 edges: 4 parallel masked gathers
        bool ok[4];
        int c[4];
#pragma unroll
        for (int j = 0; j < 4; ++j) {
            int idx = e + 4 * j + qe;
            ok[j] = idx < end;
            c[j] = (int)__builtin_nontemporal_load(col + (ok[j] ? idx : beg));
        }
#pragma unroll
        for (int j = 0; j < 4; ++j) {
            uint4 v = *(const uint4*)(xsrc + (size_t)c[j] * HDIM);
            a[j][0] += ok[j] ? __uint_as_float(v.x << 16) : 0.f;
            a[j][1] += ok[j] ? __uint_as_float(v.x & 0xffff0000u) : 0.f;
            a[j][2] += ok[j] ? __uint_as_float(v.y << 16) : 0.f;
            a[j][3] += ok[j] ? __uint_as_float(v.y & 0xffff0000u) : 0.f;
            a[j][4] += ok[j] ? __uint_as_float(v.z << 16) : 0.f;
            a[j][5] += ok[j] ? __uint_as_float(v.z & 0xffff0000u) : 0.f;
            a[j][6] += ok[j] ? __uint_as_float(v.w << 16) : 0.f;
            a[j][7] += ok[j] ? __uint_as_float(v.w & 0xffff0000u) : 0.f;
        }
    }

    float s[8];
#pragma unroll
    for (int k = 0; k < 8; ++k) {
        s[k] = (a[0][k] + a[1][k]) + (a[2][k] + a[3][k]);
        s[k] += __shfl_xor(s[k], 16);   // all lanes execute (R10 bpermute rule)
        s[k] += __shfl_xor(s[k], 32);
    }

    if (qe == 0) {
        uint4e o;
        o.x = (uint_t)f2bf(s[0]) | ((uint_t)f2bf(s[1]) << 16);
        o.y = (uint_t)f2bf(s[2]) | ((uint_t)f2bf(s[3]) << 16);
        o.z = (uint_t)f2bf(s[4]) | ((uint_t)f2bf(s[5]) << 16);
        o.w = (uint_t)f2bf(s[6]) | ((uint_t)f2bf(s[7]) << 16);
        __builtin_nontemporal_store(o, (uint4e*)(aggbuf + (size_t)node * HDIM + il * 8));
    }
}

// -------- single-pass MFMA GEMM: 256-thr block = 32 rows x full N=128 (A read once) --
// A = [agg(128) | x(128)]: left from aggbuf, right from xrow (both row-major 256 B).

template<int POOL>
__global__ __launch_bounds__(256) void k_gemm256(const ushort_t* __restrict__ aggbuf,
                                                 const ushort_t* __restrict__ xrow,
                                                 const ushort_t* __restrict__ Wfrag,
                                                 const float* __restrict__ bias,
                                                 ushort_t* __restrict__ y,
                                                 float* __restrict__ pooled) {
    __shared__ ushort_t At[32][LDSW];
    int tid = threadIdx.x;
    int w = tid >> 6;
    int lane = tid & 63;
    int row0 = blockIdx.x * 32;

#pragma unroll
    for (int it = 0; it < 4; ++it) {
        int idx = it * 256 + tid;     // 0..1023
        int r = idx >> 5;
        int c16 = idx & 31;
        uint4 v;
        if (c16 < 16) {
            v = *(const uint4*)(aggbuf + (size_t)(row0 + r) * HDIM + c16 * 8);
        } else {
            v = *(const uint4*)(xrow + (size_t)(row0 + r) * HDIM + (c16 - 16) * 8);
        }
        *(uint4*)&At[r][c16 * 8] = v;
    }
    __syncthreads();

    int m = lane & 31;
    int half = lane >> 5;
    f32x16 acc = (f32x16)(0.f);
    float bb = bias[w * 32 + m];
    const ushort_t* arow = &At[m][half * 8];
    const ushort_t* wf = Wfrag + (size_t)lane * 8;

#pragma unroll
    for (int s = 0; s < 16; ++s) {
        bf16x8 afrag = *(const bf16x8*)(arow + s * 16);
        bf16x8 bfrag = *(const bf16x8*)(wf + (size_t)(w * 16 + s) * 512);
        acc = __builtin_amdgcn_mfma_f32_32x32x16_bf16(afrag, bfrag, acc, 0, 0, 0);
    }

    if (POOL == 0) {
        __syncthreads();   // all waves done reading At; reuse it for the y transpose
#pragma unroll
        for (int r = 0; r < 16; ++r) {
            int rowL = (r & 3) + 8 * (r >> 2) + 4 * half;
            At[rowL][w * 32 + m] = f2bf(fmaxf(acc[r] + bb, 0.f));
        }
        __syncthreads();
#pragma unroll
        for (int it = 0; it < 2; ++it) {
            int c = it * 256 + tid;
            int row = c >> 4;
            int sg = c & 15;
            *(int4*)(y + (size_t)(row0 + row) * HDIM + sg * 8) = *(const int4*)&At[row][sg * 8];
        }
    } else {
        int g0 = row0 / SEG;
        int bnd = (g0 + 1) * SEG;
        int straddle = (row0 + 31 >= bnd);
        float s0 = 0.f, s1 = 0.f;
#pragma unroll
        for (int r = 0; r < 16; ++r) {
            int row = row0 + (r & 3) + 8 * (r >> 2) + 4 * half;
            float v = fmaxf(acc[r] + bb, 0.f);
            if (row < bnd) s0 += v; else s1 += v;
        }
        s0 += __shfl_xor(s0, 32);
        s1 += __shfl_xor(s1, 32);
        if (half == 0) {
            int coln = w * 32 + m;
            atomicAdd(&pooled[g0 * HDIM + coln], s0);
            if (straddle) atomicAdd(&pooled[(g0 + 1) * HDIM + coln], s1);
        }
    }
}

// ---------------- mixup: bf16 y -> xrow ----------------

__global__ void k_mixup_toA(const ushort_t* __restrict__ y, const int* __restrict__ perm,
                            const float* __restrict__ lam, ushort_t* __restrict__ xrow) {
    int idx = blockIdx.x * 256 + threadIdx.x;
    int row = idx >> 5;
    int c4 = (idx & 31) * 4;
    float l = lam[0];
    float om = 1.f - l;
    int p = perm[row];
    ushort4 a = *(const ushort4*)(y + (size_t)row * HDIM + c4);
    ushort4 b = *(const ushort4*)(y + (size_t)p * HDIM + c4);
    ushort4 o;
    o.x = f2bf(l * bf2f(a.x) + om * bf2f(b.x));
    o.y = f2bf(l * bf2f(a.y) + om * bf2f(b.y));
    o.z = f2bf(l * bf2f(a.z) + om * bf2f(b.z));
    o.w = f2bf(l * bf2f(a.w) + om * bf2f(b.w));
    *(ushort4*)(xrow + (size_t)row * HDIM + c4) = o;
}

// ---------------- final: linear + log_softmax from pooled ----------------

__global__ __launch_bounds__(64) void k_final(const float* __restrict__ pooled,
                                              const float* __restrict__ Wlin,
                                              const float* __restrict__ blin,
                                              float* __restrict__ out) {
    int g = blockIdx.x;
    int lane = threadIdx.x;
    float2 v = *(const float2*)(pooled + (size_t)g * HDIM + lane * 2);
    float p[NOUT];
#pragma unroll
    for (int o = 0; o < NOUT; ++o)
        p[o] = v.x * Wlin[(size_t)(2 * lane) * NOUT + o] +
               v.y * Wlin[(size_t)(2 * lane + 1) * NOUT + o];
#pragma unroll
    for (int mask = 1; mask < 64; mask <<= 1)
#pragma unroll
        for (int o = 0; o < NOUT; ++o) p[o] += __shfl_xor(p[o], mask);
    if (lane == 0) {
        float lg[NOUT];
        float mx = -1e30f;
#pragma unroll
        for (int o = 0; o < NOUT; ++o) { lg[o] = p[o] + blin[o]; mx = fmaxf(mx, lg[o]); }
        float se = 0.f;
#pragma unroll
        for (int o = 0; o < NOUT; ++o) se += expf(lg[o] - mx);
        float lse = mx + logf(se);
#pragma unroll
        for (int o = 0; o < NOUT; ++o) out[g * NOUT + o] = lg[o] - lse;
    }
}

// ---------------- host ----------------

extern "C" void kernel_launch(void* const* d_in, const int* in_sizes, int n_in,
                              void* d_out, int out_size, void* d_ws, size_t ws_size,
                              hipStream_t stream) {
    const float* x0     = (const float*)d_in[0];
    const int*   edge   = (const int*)d_in[1];
    const int*   src    = edge;
    const int*   dst    = edge + N_EDGES;
    const float* lam    = (const float*)d_in[2];
    const int*   perm1  = (const int*)d_in[5];
    const int*   perm2  = (const int*)d_in[6];
    const float* W1_rel = (const float*)d_in[8];
    const float* b1_rel = (const float*)d_in[9];
    const float* W1_root= (const float*)d_in[10];
    const float* W2_rel = (const float*)d_in[11];
    const float* b2_rel = (const float*)d_in[12];
    const float* W2_root= (const float*)d_in[13];
    const float* W_lin  = (const float*)d_in[14];
    const float* b_lin  = (const float*)d_in[15];
    float* out = (float*)d_out;

    char* w = (char*)d_ws;
    size_t off = 0;
    auto alloc = [&](size_t bytes) -> void* {
        void* p = w + off;
        off = (off + bytes + 255) & ~(size_t)255;
        return p;
    };
    int* cnt        = (int*)alloc((size_t)N_NODES * 4);
    ushort_t* col2  = (ushort_t*)alloc((size_t)N_NODES * SLOT * 2);
    ushort_t* xrow  = (ushort_t*)alloc((size_t)N_NODES * HDIM * 2);
    ushort_t* aggbuf= (ushort_t*)alloc((size_t)N_NODES * HDIM * 2);
    ushort_t* ybuf  = (ushort_t*)alloc((size_t)N_NODES * HDIM * 2);
    ushort_t* Wfrag1= (ushort_t*)alloc(32768 * 2);
    ushort_t* Wfrag2= (ushort_t*)alloc(32768 * 2);
    float* pooled   = (float*)alloc((size_t)NGRAPH * HDIM * 4);

    // block-histogram matrix aliases ybuf (10.24 MB <= 13.1 MB): ybuf is dead
    // until the layer-1 GEMM writes it, strictly after k_place completes.
    uint_t* bh = (uint_t*)ybuf;

    // prep (+ CSR count blocks first, overlapping the BW-bound cast blocks)
    k_prep<<<6920, 256, 0, stream>>>(x0, xrow, W1_rel, W1_root, W2_rel, W2_root,
                                     Wfrag1, Wfrag2, pooled, dst, bh);
    k_prefix<<<HISTW / 32, 256, 0, stream>>>(bh, cnt);
    k_place<<<NBLK, 256, 0, stream>>>(src, dst, bh, col2);

    const int aggGrid  = N_NODES / 4;   // 12800
    const int gemmGrid = N_NODES / 32;  // 1600
    const int elGrid   = (N_NODES * HDIM / 4) / 256;  // 6400

    // layer 1
    k_aggregate<<<aggGrid, 256, 0, stream>>>(xrow, aggbuf, cnt, col2);
    k_gemm256<0><<<gemmGrid, 256, 0, stream>>>(aggbuf, xrow, Wfrag1, b1_rel, ybuf, pooled);
    k_mixup_toA<<<elGrid, 256, 0, stream>>>(ybuf, perm1, lam, xrow);
    // layer 2
    k_aggregate<<<aggGrid, 256, 0, stream>>>(xrow, aggbuf, cnt, col2);
    k_gemm256<0><<<gemmGrid, 256, 0, stream>>>(aggbuf, xrow, Wfrag2, b2_rel, ybuf, pooled);
    k_mixup_toA<<<elGrid, 256, 0, stream>>>(ybuf, perm2, lam, xrow);
    // layer 3 (mixup3 is a pooling no-op -> fused pool)
    k_aggregate<<<aggGrid, 256, 0, stream>>>(xrow, aggbuf, cnt, col2);
    k_gemm256<1><<<gemmGrid, 256, 0, stream>>>(aggbuf, xrow, Wfrag2, b2_rel, ybuf, pooled);

    // classifier + log_softmax
    k_final<<<NGRAPH, 64, 0, stream>>>(pooled, W_lin, b_lin, out);
}